// Round 5
// baseline (295.715 us; speedup 1.0000x reference)
//
#include <hip/hip_runtime.h>
#include <hip/hip_bf16.h>

#define BB 8
#define TT 4
#define NN 4096
#define UU 64
#define EE 65536
#define BN (BB*NN)   // 32768
#define CAP 64
#define NEG 0.2f

// ws layout (float offsets); hp/es/ed ping-pong by t parity
#define OFF_XT   0                      // 12*BN  (t,f,row)
#define OFF_HP0  (12*BN)                // BN*64 row-major h'
#define OFF_HP1  (OFF_HP0 + 64*BN)
#define OFF_ES0  (OFF_HP1 + 64*BN)     // BN
#define OFF_ES1  (OFF_ES0 + BN)
#define OFF_ED0  (OFF_ES1 + BN)
#define OFF_ED1  (OFF_ED0 + BN)
#define OFF_CNT  (OFF_ED1 + BN)        // NN ints
#define OFF_SLOT (OFF_CNT + NN)        // NN*CAP ints (ends ~19.9 MB)

// XCD-aware block remap: grid = 512 = 8 batches x 64 blocks; 8 XCDs round-robin
// on blockIdx => pin batch i to XCD i so hp/es/ed/slot stay L2-resident per XCD.
// Bijective for gridDim.x == 512. (R2: FETCH 42.9->7.4 MB per step; keep.)
__device__ __forceinline__ int xcd_remap(int bid) {
  return ((bid & 7) << 6) | (bid >> 3);
}

__global__ __launch_bounds__(256) void k_conv_x(const float* x, float* xT) {
  int i = blockIdx.x * 256 + threadIdx.x;     // < 12*BN
  int r = i & (BN - 1);
  int tf = i >> 15;
  int t = tf / 3, f = tf - 3 * t;
  int b = r >> 12, n = r & (NN - 1);
  xT[i] = x[(((b * TT + t) * NN + n) * 3) + f];
}

__global__ __launch_bounds__(256) void k_fill(const int* src, const int* dst,
                                              int* cnt, int* slot) {
  int i = blockIdx.x * 256 + threadIdx.x;
  if (i < EE) {
    int d = dst[i];
    int p = atomicAdd(&cnt[d], 1);
    if (p < CAP) slot[d * CAP + p] = src[i];
  } else if (i < EE + NN) {
    int n = i - EE;
    int p = atomicAdd(&cnt[n], 1);
    if (p < CAP) slot[n * CAP + p] = n;
  }
}

// GAT at t=0 (h == 0): h' = x_0 @ gat_W[64:67]; es/ed. Writes buffer 0.
__global__ __launch_bounds__(512) void k_gat0(float* ws, const float* gW,
                                              const float* as_, const float* ad_) {
  const float* xT = ws + OFF_XT;
  float* hp = ws + OFF_HP0;
  float* es = ws + OFF_ES0;
  float* ed = ws + OFF_ED0;
  int wave = __builtin_amdgcn_readfirstlane(threadIdx.x >> 6);
  int lane = threadIdx.x & 63;
  int lb = xcd_remap(blockIdx.x);
  int row = lb * 64 + lane;
  int u0 = wave * 8;
  float acc[8];
#pragma unroll
  for (int j = 0; j < 8; ++j) acc[j] = 0.f;
#pragma unroll
  for (int k = 0; k < 3; ++k) {
    float ck = xT[k * BN + row];   // t=0
#pragma unroll
    for (int j = 0; j < 8; ++j) acc[j] += ck * gW[(64 + k) * 64 + u0 + j];
  }
  float esa = 0.f, eda = 0.f;
#pragma unroll
  for (int j = 0; j < 8; ++j) {
    esa += acc[j] * as_[u0 + j];
    eda += acc[j] * ad_[u0 + j];
  }
  float4* o = (float4*)(hp + (size_t)row * 64 + u0);
  o[0] = make_float4(acc[0], acc[1], acc[2], acc[3]);
  o[1] = make_float4(acc[4], acc[5], acc[6], acc[7]);
  __shared__ float esL[8][64], edL[8][64];
  esL[wave][lane] = esa;
  edL[wave][lane] = eda;
  __syncthreads();
  if (wave == 0) {
    float s = 0.f;
#pragma unroll
    for (int w = 0; w < 8; ++w) s += esL[w][lane];
    es[row] = s;
  } else if (wave == 1) {
    float s = 0.f;
#pragma unroll
    for (int w = 0; w < 8; ++w) s += edL[w][lane];
    ed[row] = s;
  }
}

// Fused step: attn(t) -> GRU(t) -> [GAT(t+1) | out head].
// R5: BARRIER-FREE wave-local structure. 512 thr, 8 waves, 64 rows/block,
// grid = BN/64 = 512. Wave w owns rows 8w..8w+7 end-to-end:
//  - P1 (attention) writes sL[row][u=lane] for its own 8 rows.
//  - GRU/GAT phases: lane = u; weights are lane-varying COALESCED VECTOR loads
//    (vmcnt, pipelined) -- no scalar s_loads mixed into lgkmcnt streams.
//  - sL/rsL read as uniform-address ds_read_b128 broadcasts (conflict-free).
//  - All producer->consumer edges are within one wave => zero __syncthreads.
//  - es/ed reductions: in-wave shfl butterflies (no LDS round-trip).
__global__ __launch_bounds__(512, 4) void k_step(
    float* ws, const float* gb, const float* g1W, const float* g1b,
    const float* g2W, const float* g2b, const float* gW, const float* as_,
    const float* ad_, const float* oW, const float* ob, float* out, int t,
    int last) {
  const float* xT = ws + OFF_XT;
  int pr = t & 1;
  const float* hpR = ws + (pr ? OFF_HP1 : OFF_HP0);
  const float* esR = ws + (pr ? OFF_ES1 : OFF_ES0);
  const float* edR = ws + (pr ? OFF_ED1 : OFF_ED0);
  float* hpW = ws + (pr ? OFF_HP0 : OFF_HP1);
  float* esW = ws + (pr ? OFF_ES0 : OFF_ES1);
  float* edW = ws + (pr ? OFF_ED0 : OFF_ED1);
  const int* cnt = (const int*)(ws + OFF_CNT);
  const int* slot = (const int*)(ws + OFF_SLOT);

  int wave = __builtin_amdgcn_readfirstlane(threadIdx.x >> 6);  // 0..7
  int lane = threadIdx.x & 63;
  int lb = xcd_remap(blockIdx.x);
  int rowbase = lb * 64;
  int b = rowbase / NN;
  int nbase = rowbase - b * NN;
  __shared__ float sL[64][64];    // [row][u]; rows 8w..8w+7 private to wave w
  __shared__ float rsL[64][64];
  float gbv = gb[lane];           // lane = u throughout
  int r0 = wave * 8;

  // ---- P1: attention, 8 rows per wave; store sL[row][u=lane] ----
#pragma unroll 1
  for (int rr = 0; rr < 8; ++rr) {
    int lr = r0 + rr;
    int n = nbase + lr;
    int grow = b * NN + n;
    int deg = min(cnt[n], CAP);
    float edv = edR[grow];
    int sl = (lane < deg) ? slot[n * CAP + lane] : 0;
    float e;
    if (lane < deg) {
      e = esR[b * NN + sl] + edv;
      e = e > 0.f ? e : NEG * e;
    } else {
      e = -1e30f;
    }
    float m = e;
#pragma unroll
    for (int o = 32; o >= 1; o >>= 1) m = fmaxf(m, __shfl_xor(m, o, 64));
    float w = (lane < deg) ? __expf(e - m) : 0.f;
    float dsum = w;
#pragma unroll
    for (int o = 32; o >= 1; o >>= 1) dsum += __shfl_xor(dsum, o, 64);
    w *= 1.f / dsum;
    float acc = 0.f;
#pragma unroll 1
    for (int i0 = 0; i0 < deg; i0 += 8) {
      int sis[8];
      float wv[8];
#pragma unroll
      for (int j = 0; j < 8; ++j) {
        int i = i0 + j;
        sis[j] = __shfl(sl, i, 64);
        float t_ = __shfl(w, i, 64);
        wv[j] = (i < deg) ? t_ : 0.f;
      }
      float v[8];
#pragma unroll
      for (int j = 0; j < 8; ++j)
        v[j] = hpR[(size_t)(b * NN + sis[j]) * 64 + lane];
#pragma unroll
      for (int j = 0; j < 8; ++j) acc += wv[j] * v[j];
    }
    sL[lr][lane] = acc + gbv;    // [row][u]
  }
  // no barrier: all consumers below read only rows r0..r0+7 (own wave)

  float b1r = g1b[lane];
  float b1u = g1b[64 + lane];
  float b2v = g2b[lane];

  // ---- Phase A: r and u gate pre-activations for 8 rows (lane = u) ----
  float aR[8], aU[8];
#pragma unroll
  for (int r = 0; r < 8; ++r) { aR[r] = 0.f; aU[r] = 0.f; }
#pragma unroll
  for (int k3 = 0; k3 < 3; ++k3) {
    float wl = g1W[k3 * 128 + lane];
    float wh = g1W[k3 * 128 + 64 + lane];
#pragma unroll
    for (int r = 0; r < 8; ++r) {
      float xk = xT[(t * 3 + k3) * BN + rowbase + r0 + r];
      aR[r] += xk * wl;
      aU[r] += xk * wh;
    }
  }
#pragma unroll 2
  for (int k = 0; k < 64; k += 4) {
    float wl[4], wh[4];
#pragma unroll
    for (int i = 0; i < 4; ++i) {
      wl[i] = g1W[(3 + k + i) * 128 + lane];
      wh[i] = g1W[(3 + k + i) * 128 + 64 + lane];
    }
#pragma unroll
    for (int r = 0; r < 8; ++r) {
      float4 sb = *(const float4*)&sL[r0 + r][k];   // uniform-addr broadcast
      aR[r] += sb.x * wl[0] + sb.y * wl[1] + sb.z * wl[2] + sb.w * wl[3];
      aU[r] += sb.x * wh[0] + sb.y * wh[1] + sb.z * wh[2] + sb.w * wh[3];
    }
  }
  float ug[8], sv[8];
#pragma unroll
  for (int r = 0; r < 8; ++r) {
    sv[r] = sL[r0 + r][lane];
    float rg = 1.f / (1.f + __expf(-(aR[r] + b1r)));
    rsL[r0 + r][lane] = rg * sv[r];
    ug[r] = 1.f / (1.f + __expf(-(aU[r] + b1u)));
  }

  // ---- Phase B: candidate + state update (h in regs + sL) ----
  float aC[8];
#pragma unroll
  for (int r = 0; r < 8; ++r) aC[r] = 0.f;
#pragma unroll
  for (int k3 = 0; k3 < 3; ++k3) {
    float wc = g2W[k3 * 64 + lane];
#pragma unroll
    for (int r = 0; r < 8; ++r) {
      float xk = xT[(t * 3 + k3) * BN + rowbase + r0 + r];
      aC[r] += xk * wc;
    }
  }
#pragma unroll 2
  for (int k = 0; k < 64; k += 4) {
    float wc[4];
#pragma unroll
    for (int i = 0; i < 4; ++i) wc[i] = g2W[(3 + k + i) * 64 + lane];
#pragma unroll
    for (int r = 0; r < 8; ++r) {
      float4 rb = *(const float4*)&rsL[r0 + r][k];
      aC[r] += rb.x * wc[0] + rb.y * wc[1] + rb.z * wc[2] + rb.w * wc[3];
    }
  }
  float hreg[8];
#pragma unroll
  for (int r = 0; r < 8; ++r) {
    float z = aC[r] + b2v;
    float c = 1.f - 2.f / (__expf(2.f * z) + 1.f);
    hreg[r] = ug[r] * sv[r] + (1.f - ug[r]) * c;
    sL[r0 + r][lane] = hreg[r];   // h -> sL (own rows)
  }

  if (!last) {
    // ---- P5: GAT for step t+1 on own rows' h ----
    float aG[8];
#pragma unroll
    for (int r = 0; r < 8; ++r) aG[r] = 0.f;
#pragma unroll
    for (int k3 = 0; k3 < 3; ++k3) {
      float wg = gW[(64 + k3) * 64 + lane];
#pragma unroll
      for (int r = 0; r < 8; ++r) {
        float xk = xT[((t + 1) * 3 + k3) * BN + rowbase + r0 + r];
        aG[r] += xk * wg;
      }
    }
#pragma unroll 2
    for (int k = 0; k < 64; k += 4) {
      float wg[4];
#pragma unroll
      for (int i = 0; i < 4; ++i) wg[i] = gW[(k + i) * 64 + lane];
#pragma unroll
      for (int r = 0; r < 8; ++r) {
        float4 hb = *(const float4*)&sL[r0 + r][k];
        aG[r] += hb.x * wg[0] + hb.y * wg[1] + hb.z * wg[2] + hb.w * wg[3];
      }
    }
    float asv = as_[lane], adv = ad_[lane];
#pragma unroll 1
    for (int r = 0; r < 8; ++r) {
      int row = rowbase + r0 + r;
      hpW[(size_t)row * 64 + lane] = aG[r];
      float pe = aG[r] * asv;
      float pd = aG[r] * adv;
#pragma unroll
      for (int o = 32; o >= 1; o >>= 1) {
        pe += __shfl_xor(pe, o, 64);
        pd += __shfl_xor(pd, o, 64);
      }
      if (lane == 0) {
        esW[row] = pe;
        edW[row] = pd;
      }
    }
  } else {
    // ---- P5': output head out[row,:] = h . oW + ob ----
    float w0 = oW[lane * 3 + 0];
    float w1 = oW[lane * 3 + 1];
    float w2 = oW[lane * 3 + 2];
    float ob0 = ob[0], ob1 = ob[1], ob2 = ob[2];
#pragma unroll 1
    for (int r = 0; r < 8; ++r) {
      int row = rowbase + r0 + r;
      float o0 = hreg[r] * w0;
      float o1 = hreg[r] * w1;
      float o2 = hreg[r] * w2;
#pragma unroll
      for (int o = 32; o >= 1; o >>= 1) {
        o0 += __shfl_xor(o0, o, 64);
        o1 += __shfl_xor(o1, o, 64);
        o2 += __shfl_xor(o2, o, 64);
      }
      if (lane == 0) {
        out[(size_t)row * 3 + 0] = o0 + ob0;
        out[(size_t)row * 3 + 1] = o1 + ob1;
        out[(size_t)row * 3 + 2] = o2 + ob2;
      }
    }
  }
}

extern "C" void kernel_launch(void* const* d_in, const int* in_sizes, int n_in,
                              void* d_out, int out_size, void* d_ws, size_t ws_size,
                              hipStream_t stream) {
  const float* x = (const float*)d_in[0];
  const int* src = (const int*)d_in[1];
  const int* dst = (const int*)d_in[2];
  const float* gatW = (const float*)d_in[3];
  const float* asrc = (const float*)d_in[4];
  const float* adst = (const float*)d_in[5];
  const float* gatb = (const float*)d_in[6];
  const float* g1W = (const float*)d_in[7];
  const float* g1b = (const float*)d_in[8];
  const float* g2W = (const float*)d_in[9];
  const float* g2b = (const float*)d_in[10];
  const float* oW = (const float*)d_in[11];
  const float* ob = (const float*)d_in[12];
  float* ws = (float*)d_ws;
  float* out = (float*)d_out;

  hipMemsetAsync(ws + OFF_CNT, 0, NN * sizeof(int), stream);
  k_conv_x<<<(12 * BN) / 256, 256, 0, stream>>>(x, ws + OFF_XT);
  k_fill<<<(EE + NN) / 256, 256, 0, stream>>>(src, dst, (int*)(ws + OFF_CNT),
                                              (int*)(ws + OFF_SLOT));
  k_gat0<<<BN / 64, 512, 0, stream>>>(ws, gatW, asrc, adst);
  for (int t = 0; t < TT; ++t) {
    k_step<<<BN / 64, 512, 0, stream>>>(ws, gatb, g1W, g1b, g2W, g2b, gatW,
                                        asrc, adst, oW, ob, out, t,
                                        t == TT - 1 ? 1 : 0);
  }
}